// Round 15
// baseline (370.005 us; speedup 1.0000x reference)
//
#include <hip/hip_runtime.h>
#include <stdint.h>

#define TT   500
#define BB   64
#define IND  256
#define HD   512
#define OD   35

typedef __attribute__((ext_vector_type(4))) int i32x4;

// fp32 scale exactly as numpy computes it
#define SCALE_F ((float)((1.0 - 0.001) / 31.0))

__device__ __forceinline__ void load16_lds(const int8_t* g, int8_t* l) {
  __builtin_amdgcn_global_load_lds((const __attribute__((address_space(1))) void*)g,
                                   (__attribute__((address_space(3))) void*)l, 16, 0, 0);
}

// ---------------------------------------------------------------- prep + cochlea (r14 verbatim)
__global__ __launch_bounds__(256) void k_prep_cochlea(const float* __restrict__ W1,
                                                      const float* __restrict__ W2,
                                                      const float* __restrict__ W3,
                                                      const float* __restrict__ W4,
                                                      int8_t* __restrict__ wk1,
                                                      int8_t* __restrict__ wk2,
                                                      int8_t* __restrict__ wk3,
                                                      int8_t* __restrict__ wk4,
                                                      const float* __restrict__ x,
                                                      const float* __restrict__ Wch,
                                                      const float* __restrict__ cbetas,
                                                      int8_t* __restrict__ chs) {
  __shared__ float xs[TT];
  if (blockIdx.x < 2688) {
    int id = blockIdx.x * 256 + threadIdx.x;
    const float* W; int8_t* wk; int idx, K, H;
    if (id < 131072)       { idx = id;          W = W1; wk = wk1; K = 256; H = 512; }
    else if (id < 393216)  { idx = id - 131072; W = W2; wk = wk2; K = 512; H = 512; }
    else if (id < 655360)  { idx = id - 393216; W = W3; wk = wk3; K = 512; H = 512; }
    else                   { idx = id - 655360; W = W4; wk = wk4; K = 512; H = 35;  }
    int h = idx / K;
    int k = idx - h * K;
    int8_t bits = 0;
    if (h < H) {
      float w  = W[h * K + k];
      float wc = fminf(1.0f, fmaxf(0.001f, w));
      float v  = (wc - 0.001f) / SCALE_F;
      float q  = rintf(v);                 // round-half-even, matches np.round; 0..31
      bits = (int8_t)q;
    }
    wk[idx] = bits;
  } else {
    int b = blockIdx.x - 2688;
    int i = threadIdx.x;
    for (int t = threadIdx.x; t < TT; t += 256) xs[t] = x[b * TT + t];
    __syncthreads();
    float w    = Wch[i];
    float beta = fminf(1.0f, fmaxf(0.0f, cbetas[i]));
    float mem  = 0.0f;
    for (int t = 0; t < TT; ++t) {
      float cur = __fmul_rn(xs[t], w);
      int   rs  = (mem > 1.0f);
      float t2  = __fadd_rn(__fmul_rn(beta, mem), cur);
      mem = rs ? __fsub_rn(t2, 1.0f) : t2;
      int spk = (mem > 1.0f);
      chs[(size_t)(t * BB + b) * IND + i] = (int8_t)spk;
    }
  }
}

// A-staging, waves 5..7 (others' VMEM queues untouched).
// Swizzle: slot sl of row r holds global chunk (sl - 5r) & (CH-1); reads use (kc + 5r).
template<int K>
__device__ __forceinline__ void stage_a(const int8_t* __restrict__ A, int8_t* As,
                                        int b, int gnext, int w, int lane) {
  constexpr int CH = K / 16;
  constexpr int per = (CH + 2) / 3;
  int jlo = (w - 5) * per, jhi = jlo + per; if (jhi > CH) jhi = CH;
  for (int j = jlo; j < jhi; ++j) {
    int L = j * 64 + lane;
    int r = L / CH, sl = L % CH;
    int kg = (sl - 5 * r) & (CH - 1);
    int t = gnext * 64 + r; if (t > 499) t = 499;
    load16_lds(A + ((size_t)t * 64 + b) * K + kg * 16, &As[j * 1024]);
  }
}

// ---------------------------------------------------------------- fused pipelined layer
// 512 threads = 8 waves, 2 blocks/CU (LDS 81920 exactly). Roles per round g:
//   P1: w0 scans batch g (reads cur);  w1-4 MFMA batch g+1 (read As + breg)
//   B1: all-wave lgkmcnt(0) barrier
//   P2: w1-4 f64 epilogue -> cur (safe: scan g done);  w5-7 stage batch g+2 -> As
//   B2: w5-7 vmcnt(0)lgkm(0), others lgkm(0) (scan's NT stores never drained)
// MFMA wave m=w-1 owns rows (m&1)*32 x cols (m>>1)*32; its 2 B col-groups live in
// 64 VGPRs (fits 128-VGPR cap @4 waves/SIMD); ones-MFMA per row-half gives n
// (computed redundantly per col-wave; bit-exact).
template<int K, bool LAST>
__global__ __launch_bounds__(512, 4) void k_layer(const int8_t* __restrict__ A,
                                                  const int8_t* __restrict__ Bw,
                                                  const float* __restrict__ pbeta,
                                                  float* __restrict__ spk_out,
                                                  int8_t* __restrict__ s_out,
                                                  float* __restrict__ mem_out) {
  constexpr int CH = K / 16;                 // 16-B chunks per row (32 or 16)
  constexpr int KS = K / 64;                 // ks-steps (8 or 4)
  __shared__ __align__(16) int8_t Bs[64 * K];
  __shared__ __align__(16) int8_t As[64 * K];
  __shared__ float cur[64][64];
  int tid = threadIdx.x, lane = tid & 63, w = tid >> 6;
  int b, h0;
  if (LAST) { b = blockIdx.x;      h0 = 0; }
  else      { b = blockIdx.x & 63; h0 = (blockIdx.x >> 6) * 64; }
  float beta = fminf(1.0f, fmaxf(0.0f, *pbeta));
  int lr = lane & 15, lk = lane >> 4;
  const double DSCALE = (double)SCALE_F;
  const double DWMIN  = (double)0.001f;
  const i32x4 ones = {0x01010101, 0x01010101, 0x01010101, 0x01010101};

  // prologue: stage B (all 8 waves) + A batch 0 (w5-7)
#pragma unroll
  for (int i = 0; i < K / 128; ++i) {
    int L = i * 512 + tid;
    int row = L / CH, sl = L % CH;
    int kg = (sl - 5 * row) & (CH - 1);
    load16_lds(Bw + (size_t)(h0 + row) * K + kg * 16, &Bs[(i * 512 + w * 64) * 16]);
  }
  if (w >= 5) stage_a<K>(A, As, b, 0, w, lane);
  __syncthreads();

  int m  = w - 1;                            // MFMA wave id (valid for w in 1..4)
  int R0 = (m & 1) * 32, C0 = (m >> 1) * 32;
  i32x4 breg[2][KS];
  i32x4 acc[2][2], accn[2];

#define MFMA_BATCH()                                                          \
  { acc[0][0] = (i32x4){0,0,0,0}; acc[0][1] = (i32x4){0,0,0,0};               \
    acc[1][0] = (i32x4){0,0,0,0}; acc[1][1] = (i32x4){0,0,0,0};               \
    accn[0]   = (i32x4){0,0,0,0}; accn[1]   = (i32x4){0,0,0,0};               \
    _Pragma("unroll") for (int ks = 0; ks < KS; ++ks) {                       \
      int row0 = R0 + lr,      sa0 = (ks*4 + lk + 5*row0) & (CH-1);           \
      int row1 = R0 + 16 + lr, sa1 = (ks*4 + lk + 5*row1) & (CH-1);           \
      i32x4 av0 = *(const i32x4*)&As[row0 * K + sa0 * 16];                    \
      i32x4 av1 = *(const i32x4*)&As[row1 * K + sa1 * 16];                    \
      acc[0][0] = __builtin_amdgcn_mfma_i32_16x16x64_i8(av0, breg[0][ks], acc[0][0], 0,0,0); \
      acc[0][1] = __builtin_amdgcn_mfma_i32_16x16x64_i8(av0, breg[1][ks], acc[0][1], 0,0,0); \
      acc[1][0] = __builtin_amdgcn_mfma_i32_16x16x64_i8(av1, breg[0][ks], acc[1][0], 0,0,0); \
      acc[1][1] = __builtin_amdgcn_mfma_i32_16x16x64_i8(av1, breg[1][ks], acc[1][1], 0,0,0); \
      accn[0]   = __builtin_amdgcn_mfma_i32_16x16x64_i8(av0, ones, accn[0], 0,0,0); \
      accn[1]   = __builtin_amdgcn_mfma_i32_16x16x64_i8(av1, ones, accn[1], 0,0,0); \
    } }

#define EPI()                                                                 \
  { _Pragma("unroll") for (int rf = 0; rf < 2; ++rf) {                        \
      int pr = R0 + rf * 16 + lk * 4;                                         \
      _Pragma("unroll") for (int i = 0; i < 4; ++i) {                         \
        double nd = (double)accn[rf][i] * DWMIN;                              \
        cur[pr + i][C0 +  0 + lr] = (float)((double)acc[rf][0][i] * DSCALE + nd); \
        cur[pr + i][C0 + 16 + lr] = (float)((double)acc[rf][1][i] * DSCALE + nd); \
      } } }

  // hoist breg from persistent Bs; MFMA batch 0
  if (w >= 1 && w <= 4) {
#pragma unroll
    for (int cf = 0; cf < 2; ++cf)
#pragma unroll
      for (int ks = 0; ks < KS; ++ks) {
        int row = C0 + cf * 16 + lr;
        int s0 = (ks * 4 + lk + 5 * row) & (CH - 1);
        breg[cf][ks] = *(const i32x4*)&Bs[row * K + s0 * 16];
      }
    MFMA_BATCH()
  }
  // barrier: MFMA0's LDS reads done before stage1 overwrites As
  __builtin_amdgcn_sched_barrier(0);
  asm volatile("s_waitcnt lgkmcnt(0)" ::: "memory");
  __builtin_amdgcn_s_barrier();
  __builtin_amdgcn_sched_barrier(0);
  // epi0 -> cur ; stage batch 1 -> As
  if (w >= 1 && w <= 4) EPI()
  if (w >= 5) stage_a<K>(A, As, b, 1, w, lane);
  __builtin_amdgcn_sched_barrier(0);
  if (w >= 5) asm volatile("s_waitcnt vmcnt(0) lgkmcnt(0)" ::: "memory");
  else        asm volatile("s_waitcnt lgkmcnt(0)" ::: "memory");
  __builtin_amdgcn_s_barrier();
  __builtin_amdgcn_sched_barrier(0);

  float mem = 0.0f;
  for (int g = 0; g < 8; ++g) {
    // -------- P1: scan g (w0)  ||  MFMA g+1 (w1-4)
    if (w == 0) {
      float curA[16], curB[16];
#define LOADQ(dst, q)                                                         \
      { _Pragma("unroll") for (int r = 0; r < 16; ++r)                        \
          dst[r] = cur[(q) * 16 + r][lane]; }
#define CHAINQ(src, q)                                                        \
      { _Pragma("unroll") for (int r = 0; r < 16; ++r) {                      \
          int t = g * 64 + (q) * 16 + r;                                      \
          int   rs = (mem > 1.0f);                                            \
          float t2 = __fadd_rn(__fmul_rn(beta, mem), src[r]);                 \
          mem = rs ? __fsub_rn(t2, 1.0f) : t2;                                \
          int spk = (mem > 1.0f);                                             \
          if (t < 500) {                                                      \
            int row = t * 64 + b;                                             \
            if (!LAST) {                                                      \
              __builtin_nontemporal_store(spk ? 1.0f : 0.0f,                  \
                  &spk_out[(size_t)t * 32768 + (b << 9) + h0 + lane]);        \
              s_out[(size_t)row * 512 + h0 + lane] = (int8_t)spk;             \
            } else if (lane < OD) {                                           \
              __builtin_nontemporal_store(spk ? 1.0f : 0.0f,                  \
                  &spk_out[(size_t)t * (BB * OD) + b * OD + lane]);           \
              __builtin_nontemporal_store(mem,                                \
                  &mem_out[(size_t)t * (BB * OD) + b * OD + lane]);           \
            }                                                                 \
          } } }
      LOADQ(curA, 0)
      LOADQ(curB, 1)
      CHAINQ(curA, 0)
      LOADQ(curA, 2)
      CHAINQ(curB, 1)
      LOADQ(curB, 3)
      CHAINQ(curA, 2)
      CHAINQ(curB, 3)
#undef LOADQ
#undef CHAINQ
    } else if (w <= 4 && g < 7) {
      MFMA_BATCH()
    }
    // -------- B1: all LDS traffic done (scan reads + MFMA reads)
    __builtin_amdgcn_sched_barrier(0);
    asm volatile("s_waitcnt lgkmcnt(0)" ::: "memory");
    __builtin_amdgcn_s_barrier();
    __builtin_amdgcn_sched_barrier(0);
    // -------- P2: epi g+1 -> cur (w1-4)  ||  stage g+2 -> As (w5-7)
    if (w >= 1 && w <= 4 && g < 7) EPI()
    if (w >= 5 && g < 6) stage_a<K>(A, As, b, g + 2, w, lane);
    // -------- B2: staging landed; epi writes visible; scan stores NOT drained
    __builtin_amdgcn_sched_barrier(0);
    if (w >= 5) asm volatile("s_waitcnt vmcnt(0) lgkmcnt(0)" ::: "memory");
    else        asm volatile("s_waitcnt lgkmcnt(0)" ::: "memory");
    __builtin_amdgcn_s_barrier();
    __builtin_amdgcn_sched_barrier(0);
  }
#undef MFMA_BATCH
#undef EPI
}

// ---------------------------------------------------------------- launch (5 nodes)
extern "C" void kernel_launch(void* const* d_in, const int* in_sizes, int n_in,
                              void* d_out, int out_size, void* d_ws, size_t ws_size,
                              hipStream_t stream) {
  const float* x      = (const float*)d_in[0];
  const float* Wch    = (const float*)d_in[1];
  const float* W1     = (const float*)d_in[2];
  const float* W2     = (const float*)d_in[3];
  const float* W3     = (const float*)d_in[4];
  const float* W4     = (const float*)d_in[5];
  const float* cbetas = (const float*)d_in[6];
  const float* b1     = (const float*)d_in[7];
  const float* b2     = (const float*)d_in[8];
  const float* b3     = (const float*)d_in[9];
  const float* b4     = (const float*)d_in[10];

  uint8_t* ws = (uint8_t*)d_ws;
  int8_t*   wk1   = (int8_t*)(ws + 0);          // 512*256   = 131072
  int8_t*   wk2   = (int8_t*)(ws + 131072);     // 512*512   = 262144
  int8_t*   wk3   = (int8_t*)(ws + 393216);     // 262144
  int8_t*   wk4   = (int8_t*)(ws + 655360);     // 64*512    = 32768 -> 688128
  int8_t*   chs   = (int8_t*)(ws + 688128);     // 32000*256 = 8192000
  int8_t*   sbufA = (int8_t*)(ws + 8880128);    // 32000*512 = 16384000
  int8_t*   sbufB = (int8_t*)(ws + 25264128);   // -> ends 41648128

  float* out  = (float*)d_out;
  float* spk1 = out;                // 500*64*512
  float* spk2 = out + 16384000;
  float* spk3 = out + 32768000;
  float* spk4 = out + 49152000;     // 500*64*35
  float* mem4 = out + 50272000;

  // prep (blocks 0..2687) + cochlea (blocks 2688..2751), independent work
  k_prep_cochlea<<<2752, 256, 0, stream>>>(W1, W2, W3, W4, wk1, wk2, wk3, wk4,
                                           x, Wch, cbetas, chs);

  // fused pipelined layers: read buffer != write buffer
  k_layer<256, false><<<512, 512, 0, stream>>>(chs,   wk1, b1, spk1, sbufA, nullptr);
  k_layer<512, false><<<512, 512, 0, stream>>>(sbufA, wk2, b2, spk2, sbufB, nullptr);
  k_layer<512, false><<<512, 512, 0, stream>>>(sbufB, wk3, b3, spk3, sbufA, nullptr);
  k_layer<512, true ><<<64,  512, 0, stream>>>(sbufA, wk4, b4, spk4, nullptr, mem4);
}

// Round 17
// 338.932 us; speedup vs baseline: 1.0917x; 1.0917x over previous
//
#include <hip/hip_runtime.h>
#include <stdint.h>

#define TT   500
#define BB   64
#define IND  256
#define HD   512
#define OD   35

typedef __attribute__((ext_vector_type(4))) int i32x4;

// fp32 scale exactly as numpy computes it
#define SCALE_F ((float)((1.0 - 0.001) / 31.0))

__device__ __forceinline__ void load16_lds(const int8_t* g, int8_t* l) {
  __builtin_amdgcn_global_load_lds((const __attribute__((address_space(1))) void*)g,
                                   (__attribute__((address_space(3))) void*)l, 16, 0, 0);
}

// ---------------------------------------------------------------- prep + cochlea
__global__ __launch_bounds__(256) void k_prep_cochlea(const float* __restrict__ W1,
                                                      const float* __restrict__ W2,
                                                      const float* __restrict__ W3,
                                                      const float* __restrict__ W4,
                                                      int8_t* __restrict__ wk1,
                                                      int8_t* __restrict__ wk2,
                                                      int8_t* __restrict__ wk3,
                                                      int8_t* __restrict__ wk4,
                                                      const float* __restrict__ x,
                                                      const float* __restrict__ Wch,
                                                      const float* __restrict__ cbetas,
                                                      int8_t* __restrict__ chs) {
  __shared__ float xs[TT];
  if (blockIdx.x < 2688) {
    int id = blockIdx.x * 256 + threadIdx.x;
    const float* W; int8_t* wk; int idx, K, H;
    if (id < 131072)       { idx = id;          W = W1; wk = wk1; K = 256; H = 512; }
    else if (id < 393216)  { idx = id - 131072; W = W2; wk = wk2; K = 512; H = 512; }
    else if (id < 655360)  { idx = id - 393216; W = W3; wk = wk3; K = 512; H = 512; }
    else                   { idx = id - 655360; W = W4; wk = wk4; K = 512; H = 35;  }
    int h = idx / K;
    int k = idx - h * K;
    int8_t bits = 0;
    if (h < H) {
      float w  = W[h * K + k];
      float wc = fminf(1.0f, fmaxf(0.001f, w));
      float v  = (wc - 0.001f) / SCALE_F;
      float q  = rintf(v);                 // round-half-even, matches np.round; 0..31
      bits = (int8_t)q;
    }
    wk[idx] = bits;
  } else {
    int b = blockIdx.x - 2688;
    int i = threadIdx.x;
    for (int t = threadIdx.x; t < TT; t += 256) xs[t] = x[b * TT + t];
    __syncthreads();
    float w    = Wch[i];
    float beta = fminf(1.0f, fmaxf(0.0f, cbetas[i]));
    float mem  = 0.0f;
    for (int t = 0; t < TT; ++t) {
      float cur = __fmul_rn(xs[t], w);
      int   rs  = (mem > 1.0f);
      float t2  = __fadd_rn(__fmul_rn(beta, mem), cur);
      mem = rs ? __fsub_rn(t2, 1.0f) : t2;
      int spk = (mem > 1.0f);
      chs[(size_t)(t * BB + b) * IND + i] = (int8_t)spk;
    }
  }
}

// A-staging, waves 1..3 only (wave0's VMEM queue stays stores-only).
// Slot swizzle: slot sl of row r holds global chunk (sl - 5r) & (CH-1), so the
// MFMA read (kc + 5*row) hits 16 distinct slots across a wave's 16 rows -> 2-way.
template<int K>
__device__ __forceinline__ void stage_a(const int8_t* __restrict__ A, int8_t* As,
                                        int b, int gnext, int w, int lane) {
  constexpr int CH = K / 16;
  if (w > 0) {
    constexpr int per = (CH + 2) / 3;
    int jlo = (w - 1) * per, jhi = jlo + per; if (jhi > CH) jhi = CH;
    for (int j = jlo; j < jhi; ++j) {
      int L = j * 64 + lane;
      int r = L / CH, sl = L % CH;
      int kg = (sl - 5 * r) & (CH - 1);
      int t = gnext * 64 + r; if (t > 499) t = 499;
      load16_lds(A + ((size_t)t * 64 + b) * K + kg * 16, &As[j * 1024]);
    }
  }
}

// ---------------------------------------------------------------- fused layer: GEMM + LIF scan
// One block = (batch b) x (64-col slice h0); b=blk&63 keeps slice-blocks of a
// batch on one XCD. B in registers (breg). Per 64-t batch: 4-wave i8 MFMA
// (+ones-column MFMA -> n) -> f64 cur epilogue -> curbuf -> raw barrier
// (lgkm only) -> waves1-3 stage next A / wave0 scans -> raw barrier
// (waves1-3 vmcnt(0), wave0 lgkm only — NT stores never drained in-loop).
template<int K, bool LAST>
__global__ __launch_bounds__(256, 2) void k_layer(const int8_t* __restrict__ A,
                                                  const int8_t* __restrict__ Bw,
                                                  const float* __restrict__ pbeta,
                                                  float* __restrict__ spk_out,
                                                  int8_t* __restrict__ s_out,
                                                  float* __restrict__ mem_out) {
  constexpr int CH = K / 16;                 // 16-B chunks per row (32 or 16)
  constexpr int KS = K / 64;                 // ks-steps (8 or 4)
  __shared__ __align__(16) int8_t Bs[64 * K];
  __shared__ __align__(16) int8_t As[64 * K];
  __shared__ float curbuf[64][64];           // f32 cur, written by all 4 waves
  int tid = threadIdx.x, lane = tid & 63, w = tid >> 6;
  int b, h0;
  if (LAST) { b = blockIdx.x;      h0 = 0; }
  else      { b = blockIdx.x & 63; h0 = (blockIdx.x >> 6) * 64; }
  float beta = fminf(1.0f, fmaxf(0.0f, *pbeta));
  // stage B slice [64][K] (one-time, all 256 threads, new swizzle)
#pragma unroll
  for (int i = 0; i < CH / 4; ++i) {
    int L = i * 256 + tid;
    int row = L / CH, sl = L % CH;
    int kg = (sl - 5 * row) & (CH - 1);
    load16_lds(Bw + (size_t)(h0 + row) * K + kg * 16, &Bs[(i * 256 + w * 64) * 16]);
  }
  stage_a<K>(A, As, b, 0, w, lane);          // A batch 0
  __syncthreads();                           // prologue: full drain (no stores yet)
  const double DSCALE = (double)SCALE_F;
  const double DWMIN  = (double)0.001f;
  float mem = 0.0f;
  int lr = lane & 15, lk = lane >> 4;
  int arow = w * 16 + lr;
  // hoist B fragments into registers (constexpr-indexed -> VGPRs)
  i32x4 breg[4][KS];
#pragma unroll
  for (int cg = 0; cg < 4; ++cg)
#pragma unroll
    for (int ks = 0; ks < KS; ++ks) {
      int row = cg * 16 + lr;
      int s0 = (ks * 4 + lk + 5 * row) & (CH - 1);
      breg[cg][ks] = *(const i32x4*)&Bs[row * K + s0 * 16];
    }
  const i32x4 ones = {0x01010101, 0x01010101, 0x01010101, 0x01010101};
  for (int g = 0; g < 8; ++g) {
    i32x4 acc0 = {0,0,0,0}, acc1 = {0,0,0,0}, acc2 = {0,0,0,0}, acc3 = {0,0,0,0};
    i32x4 acc4 = {0,0,0,0};                  // row-sum column (n), column-constant
#pragma unroll
    for (int ks = 0; ks < KS; ++ks) {
      int s0 = (ks * 4 + lk + 5 * arow) & (CH - 1);
      i32x4 av = *(const i32x4*)&As[arow * K + s0 * 16];
      acc0 = __builtin_amdgcn_mfma_i32_16x16x64_i8(av, breg[0][ks], acc0, 0, 0, 0);
      acc1 = __builtin_amdgcn_mfma_i32_16x16x64_i8(av, breg[1][ks], acc1, 0, 0, 0);
      acc2 = __builtin_amdgcn_mfma_i32_16x16x64_i8(av, breg[2][ks], acc2, 0, 0, 0);
      acc3 = __builtin_amdgcn_mfma_i32_16x16x64_i8(av, breg[3][ks], acc3, 0, 0, 0);
      acc4 = __builtin_amdgcn_mfma_i32_16x16x64_i8(av, ones, acc4, 0, 0, 0);
    }
    // epilogue: cur = f32(f64(M)*DSCALE + f64(n)*DWMIN); D row = w*16+lk*4+i, col = cg*16+lr
    int pr = w * 16 + lk * 4;
#pragma unroll
    for (int i = 0; i < 4; ++i) {
      double nd = (double)acc4[i] * DWMIN;
      curbuf[pr + i][ 0 + lr] = (float)((double)acc0[i] * DSCALE + nd);
      curbuf[pr + i][16 + lr] = (float)((double)acc1[i] * DSCALE + nd);
      curbuf[pr + i][32 + lr] = (float)((double)acc2[i] * DSCALE + nd);
      curbuf[pr + i][48 + lr] = (float)((double)acc3[i] * DSCALE + nd);
    }
    // B1: curbuf ready + all As reads complete. LDS-only drain — no store wait.
    __builtin_amdgcn_sched_barrier(0);
    asm volatile("s_waitcnt lgkmcnt(0)" ::: "memory");
    __builtin_amdgcn_s_barrier();
    __builtin_amdgcn_sched_barrier(0);
    // waves 1-3: stage next A batch (overwrites As; reads done per B1)
    if (g < 7) stage_a<K>(A, As, b, g + 1, w, lane);
    // wave0: bare np-exact fp32 chain, quarters of 16 with 1-quarter lookahead.
    if (w == 0) {
      float curA[16], curB[16];
#define LOADQ(dst, q)                                                         \
      { _Pragma("unroll") for (int r = 0; r < 16; ++r)                        \
          dst[r] = curbuf[(q) * 16 + r][lane]; }
#define CHAINQ(src, q)                                                        \
      { _Pragma("unroll") for (int r = 0; r < 16; ++r) {                      \
          int t = g * 64 + (q) * 16 + r;                                      \
          int   rs = (mem > 1.0f);                                            \
          float t2 = __fadd_rn(__fmul_rn(beta, mem), src[r]);                 \
          mem = rs ? __fsub_rn(t2, 1.0f) : t2;                                \
          int spk = (mem > 1.0f);                                             \
          if (t < 500) {                                                      \
            int row = t * 64 + b;                                             \
            if (!LAST) {                                                      \
              __builtin_nontemporal_store(spk ? 1.0f : 0.0f,                  \
                  &spk_out[(size_t)t * 32768 + (b << 9) + h0 + lane]);        \
              s_out[(size_t)row * 512 + h0 + lane] = (int8_t)spk;             \
            } else if (lane < OD) {                                           \
              __builtin_nontemporal_store(spk ? 1.0f : 0.0f,                  \
                  &spk_out[(size_t)t * (BB * OD) + b * OD + lane]);           \
              __builtin_nontemporal_store(mem,                                \
                  &mem_out[(size_t)t * (BB * OD) + b * OD + lane]);           \
            }                                                                 \
          } } }
      LOADQ(curA, 0)
      LOADQ(curB, 1)
      CHAINQ(curA, 0)
      LOADQ(curA, 2)
      CHAINQ(curB, 1)
      LOADQ(curB, 3)
      CHAINQ(curA, 2)
      CHAINQ(curB, 3)
#undef LOADQ
#undef CHAINQ
    }
    // B2: staging landed (waves1-3 vmcnt) + wave0's curbuf reads done.
    // Wave0's NT stores are NEVER drained inside the loop (T4 principle).
    __builtin_amdgcn_sched_barrier(0);
    if (w == 0) asm volatile("s_waitcnt lgkmcnt(0)" ::: "memory");
    else        asm volatile("s_waitcnt vmcnt(0) lgkmcnt(0)" ::: "memory");
    __builtin_amdgcn_s_barrier();
    __builtin_amdgcn_sched_barrier(0);
  }
}

// ---------------------------------------------------------------- launch (5 nodes, no memset)
extern "C" void kernel_launch(void* const* d_in, const int* in_sizes, int n_in,
                              void* d_out, int out_size, void* d_ws, size_t ws_size,
                              hipStream_t stream) {
  const float* x      = (const float*)d_in[0];
  const float* Wch    = (const float*)d_in[1];
  const float* W1     = (const float*)d_in[2];
  const float* W2     = (const float*)d_in[3];
  const float* W3     = (const float*)d_in[4];
  const float* W4     = (const float*)d_in[5];
  const float* cbetas = (const float*)d_in[6];
  const float* b1     = (const float*)d_in[7];
  const float* b2     = (const float*)d_in[8];
  const float* b3     = (const float*)d_in[9];
  const float* b4     = (const float*)d_in[10];

  uint8_t* ws = (uint8_t*)d_ws;
  int8_t*   wk1   = (int8_t*)(ws + 0);          // 512*256   = 131072
  int8_t*   wk2   = (int8_t*)(ws + 131072);     // 512*512   = 262144
  int8_t*   wk3   = (int8_t*)(ws + 393216);     // 262144
  int8_t*   wk4   = (int8_t*)(ws + 655360);     // 64*512    = 32768 -> 688128
  int8_t*   chs   = (int8_t*)(ws + 688128);     // 32000*256 = 8192000
  int8_t*   sbufA = (int8_t*)(ws + 8880128);    // 32000*512 = 16384000
  int8_t*   sbufB = (int8_t*)(ws + 25264128);   // -> ends 41648128

  float* out  = (float*)d_out;
  float* spk1 = out;                // 500*64*512
  float* spk2 = out + 16384000;
  float* spk3 = out + 32768000;
  float* spk4 = out + 49152000;     // 500*64*35
  float* mem4 = out + 50272000;

  // prep (blocks 0..2687) + cochlea (blocks 2688..2751), independent work
  k_prep_cochlea<<<2752, 256, 0, stream>>>(W1, W2, W3, W4, wk1, wk2, wk3, wk4,
                                           x, Wch, cbetas, chs);

  // fused layers: read buffer != write buffer
  k_layer<256, false><<<512, 256, 0, stream>>>(chs,   wk1, b1, spk1, sbufA, nullptr);
  k_layer<512, false><<<512, 256, 0, stream>>>(sbufA, wk2, b2, spk2, sbufB, nullptr);
  k_layer<512, false><<<512, 256, 0, stream>>>(sbufB, wk3, b3, spk3, sbufA, nullptr);
  k_layer<512, true ><<<64,  256, 0, stream>>>(sbufA, wk4, b4, spk4, nullptr, mem4);
}